// Round 1
// baseline (527.375 us; speedup 1.0000x reference)
//
#include <hip/hip_runtime.h>
#include <math.h>

// Problem constants (fixed by the reference).
constexpr int Ac = 16;    // actions
constexpr int Bc = 32;    // batch
constexpr int Lc = 1024;  // sequence
constexpr int Xc = 1024;  // x feature
constexpr int Yc = 1024;  // y feature
constexpr int Cc = Ac + Bc;  // 48 combined coefficient rows

// Native clang vector type — __builtin_nontemporal_load requires this.
typedef float vfloat4 __attribute__((ext_vector_type(4)));

// ---------------------------------------------------------------------------
// Wave/block reduction helpers (wave = 64 lanes on CDNA)
// ---------------------------------------------------------------------------
__device__ __forceinline__ float waveReduceSum(float v) {
#pragma unroll
    for (int off = 32; off > 0; off >>= 1) v += __shfl_down(v, off, 64);
    return v;
}

__device__ __forceinline__ float waveReduceMax(float v) {
#pragma unroll
    for (int off = 32; off > 0; off >>= 1) v = fmaxf(v, __shfl_down(v, off, 64));
    return v;
}

// ---------------------------------------------------------------------------
// k1: O[48,X] = C[48,Y] @ W[Y,X]; C rows 0..15 = wa_h, rows 16..47 = y.
// O rows 0..15 -> s_raw (pre-softmax scores), rows 16..47 -> yW.
// grid (X/256=4, Y/32=32) = 128 blocks — all co-resident on 256 CUs, which
// makes the fused softmax safe: after every block signals completion via a
// device counter, the 16 blocks with flat-id < 16 each softmax one s_raw row
// (this deletes the standalone k2 launch; R5 fusion).
// Worker part is byte-identical to the R4-measured-best atomic split-K.
// ---------------------------------------------------------------------------
__global__ __launch_bounds__(256) void k1_proj_sm(
        const float* __restrict__ weight, const float* __restrict__ yv,
        const float* __restrict__ wa_h, float* __restrict__ s_raw,
        float* __restrict__ yW, float* __restrict__ score2,
        unsigned* __restrict__ cnt) {
    const int x  = blockIdx.x * 256 + threadIdx.x;
    const int y0 = blockIdx.y * 32;

    __shared__ float cLDS[Cc][32];  // 6 KiB

    // Cooperative coef load: 1536 elements, 6 per thread (coalesced).
#pragma unroll
    for (int k = 0; k < 6; ++k) {
        const int idx = threadIdx.x + k * 256;
        const int row = idx >> 5;
        const int col = idx & 31;
        cLDS[row][col] = (row < Ac) ? wa_h[row * Yc + y0 + col]
                                    : yv[(row - Ac) * Yc + y0 + col];
    }

    // Prefetch this thread's 32 weight values (independent, coalesced).
    float w[32];
#pragma unroll
    for (int t = 0; t < 32; ++t) w[t] = weight[(size_t)(y0 + t) * Xc + x];

    __syncthreads();

    float acc[Cc];
#pragma unroll
    for (int j = 0; j < Cc; ++j) acc[j] = 0.0f;

    const float4* cvec = (const float4*)cLDS;
#pragma unroll
    for (int j = 0; j < Cc; ++j) {
#pragma unroll
        for (int q = 0; q < 8; ++q) {
            const float4 c = cvec[j * 8 + q];  // LDS b128 broadcast (free)
            acc[j] = fmaf(w[q * 4 + 0], c.x, acc[j]);
            acc[j] = fmaf(w[q * 4 + 1], c.y, acc[j]);
            acc[j] = fmaf(w[q * 4 + 2], c.z, acc[j]);
            acc[j] = fmaf(w[q * 4 + 3], c.w, acc[j]);
        }
    }

#pragma unroll
    for (int j = 0; j < Ac; ++j) atomicAdd(&s_raw[j * Xc + x], acc[j]);
#pragma unroll
    for (int j = Ac; j < Cc; ++j) atomicAdd(&yW[(j - Ac) * Xc + x], acc[j]);

    // ---- completion signal (release) ----
    __threadfence();
    __syncthreads();
    if (threadIdx.x == 0) atomicAdd(cnt, 1u);

    // ---- fused k2: 16 designated blocks softmax one row each ----
    const int fid = blockIdx.y * gridDim.x + blockIdx.x;  // 0..127
    if (fid >= Ac) return;

    const unsigned total = gridDim.x * gridDim.y;  // 128
    if (threadIdx.x == 0) {
        while (__hip_atomic_load(cnt, __ATOMIC_ACQUIRE,
                                 __HIP_MEMORY_SCOPE_AGENT) < total)
            __builtin_amdgcn_s_sleep(2);
    }
    __syncthreads();

    const int a    = fid;
    const int tid  = threadIdx.x;
    const int wave = tid >> 6;
    const int lane = tid & 63;
    __shared__ float smax[4];
    __shared__ float ssum[4];

    float v[4];
    float mx = -INFINITY;
#pragma unroll
    for (int k = 0; k < 4; ++k) {
        // Agent-scope loads: read at the coherent point (s_raw was produced
        // by other XCDs' atomics).
        v[k] = __hip_atomic_load(&s_raw[a * Xc + tid + k * 256],
                                 __ATOMIC_RELAXED, __HIP_MEMORY_SCOPE_AGENT);
        mx = fmaxf(mx, v[k]);
    }
    mx = waveReduceMax(mx);
    if (lane == 0) smax[wave] = mx;
    __syncthreads();
    mx = fmaxf(fmaxf(smax[0], smax[1]), fmaxf(smax[2], smax[3]));

    float sum = 0.0f;
#pragma unroll
    for (int k = 0; k < 4; ++k) {
        v[k] = __expf(v[k] - mx);
        sum += v[k];
    }
    sum = waveReduceSum(sum);
    if (lane == 0) ssum[wave] = sum;
    __syncthreads();
    sum = ssum[0] + ssum[1] + ssum[2] + ssum[3];

    const float inv = 1.0f / sum;
#pragma unroll
    for (int k = 0; k < 4; ++k) score2[a * Xc + tid + k * 256] = v[k] * inv;
}

// ---------------------------------------------------------------------------
// k3: xWy[b,l] = sum_x x[b,l,x] * Wy[b,x],
//     Wy[b,x] = yW[b,x]*score2[actions[b],x] + bias[x]  (built once in LDS).
// grid: (L/16, B) = 2048 blocks, 4 waves; each wave 4 rows. Streams all
// 128 MB of x (HBM floor ~19 us) — nontemporal: x has zero reuse, skip L2.
// Fused k4 (R5): per-b completion counter; the LAST block for batch b
// re-reads xWy[b,:] (agent scope) and computes the log-softmax row inline —
// deletes the standalone 32-block k4 launch. Dot part is R2-measured-best.
// ---------------------------------------------------------------------------
__global__ __launch_bounds__(256) void k3_dot_lsm(
        const float* __restrict__ x, const float* __restrict__ yW,
        const float* __restrict__ score2, const float* __restrict__ bias,
        const int* __restrict__ actions, const unsigned char* __restrict__ mask,
        float* __restrict__ xWy, float* __restrict__ out,
        unsigned* __restrict__ cnt3) {
    const int b  = blockIdx.y;
    const int l0 = blockIdx.x * 16;
    __shared__ float Wy[Xc];

    const int act = actions[b];
#pragma unroll
    for (int k = 0; k < 4; ++k) {
        const int xi = threadIdx.x + k * 256;
        Wy[xi] = fmaf(yW[b * Xc + xi], score2[act * Xc + xi], bias[xi]);
    }
    __syncthreads();

    const int wave = threadIdx.x >> 6;
    const int lane = threadIdx.x & 63;
    const float4* WyV = (const float4*)Wy;

    for (int r = wave; r < 16; r += 4) {
        const int l = l0 + r;
        const vfloat4* xp = (const vfloat4*)(x + ((size_t)b * Lc + l) * Xc);
        float acc = 0.0f;
#pragma unroll
        for (int k = 0; k < 4; ++k) {
            const int idx = lane + k * 64;
            const vfloat4 xv = __builtin_nontemporal_load(&xp[idx]);
            const float4 wv = WyV[idx];
            acc = fmaf(xv.x, wv.x, acc);
            acc = fmaf(xv.y, wv.y, acc);
            acc = fmaf(xv.z, wv.z, acc);
            acc = fmaf(xv.w, wv.w, acc);
        }
        acc = waveReduceSum(acc);
        if (lane == 0) xWy[b * Lc + l] = acc;
    }

    // ---- completion signal; last block for this b does the log-softmax ----
    __threadfence();
    __syncthreads();
    __shared__ int lastFlag;
    if (threadIdx.x == 0) {
        const unsigned old = atomicAdd(&cnt3[b], 1u);
        lastFlag = (old == gridDim.x - 1);
    }
    __syncthreads();
    if (!lastFlag) return;

    const int tid  = threadIdx.x;
    const int wv   = tid >> 6;
    const int ln   = tid & 63;
    __shared__ float smax[4];
    __shared__ float ssum[4];

    float v[4];
    float mx = -INFINITY;
#pragma unroll
    for (int k = 0; k < 4; ++k) {
        const int l = tid + k * 256;
        float t = __hip_atomic_load(&xWy[b * Lc + l], __ATOMIC_RELAXED,
                                    __HIP_MEMORY_SCOPE_AGENT);
        if (mask[b * Lc + l]) t = -INFINITY;
        v[k] = t;
        mx = fmaxf(mx, t);
    }
    mx = waveReduceMax(mx);
    if (ln == 0) smax[wv] = mx;
    __syncthreads();
    mx = fmaxf(fmaxf(smax[0], smax[1]), fmaxf(smax[2], smax[3]));

    float sum = 0.0f;
#pragma unroll
    for (int k = 0; k < 4; ++k) sum += __expf(v[k] - mx);
    sum = waveReduceSum(sum);
    if (ln == 0) ssum[wv] = sum;
    __syncthreads();
    sum = ssum[0] + ssum[1] + ssum[2] + ssum[3];

    const float lse = mx + __logf(sum);
#pragma unroll
    for (int k = 0; k < 4; ++k) out[b * Lc + tid + k * 256] = v[k] - lse;
}

// ---------------------------------------------------------------------------
// Launch. Inputs (setup_inputs order):
//   0 x      [B,L,X] f32      1 y      [B,Y] f32     2 x_mask [B,L] bool
//   3 actions[B] int32        4 weight [Y,X] f32     5 bias   [X] f32
//   6 wa_h   [A,Y,1] f32
// Output: [B,L] f32 log-softmax.
// Workspace layout (zeroed region first so one memset covers counters+accum):
//   [0,128)        cnt3    32 u32 (per-b k3 completion counters)
//   [128,132)      cnt1    1 u32  (k1 completion counter)
//   [4K,68K)       s_raw   A*X f32 (atomic-accumulated)
//   [68K,196K)     yW      B*X f32 (atomic-accumulated)
//   [196K,260K)    score2  A*X f32
//   [260K,388K)    xWy     B*L f32
// ---------------------------------------------------------------------------
extern "C" void kernel_launch(void* const* d_in, const int* in_sizes, int n_in,
                              void* d_out, int out_size, void* d_ws, size_t ws_size,
                              hipStream_t stream) {
    const float* x          = (const float*)d_in[0];
    const float* yv         = (const float*)d_in[1];
    const unsigned char* xm = (const unsigned char*)d_in[2];
    const int* actions      = (const int*)d_in[3];
    const float* weight     = (const float*)d_in[4];
    const float* bias       = (const float*)d_in[5];
    const float* wa_h       = (const float*)d_in[6];
    float* out              = (float*)d_out;

    char* ws        = (char*)d_ws;
    unsigned* cnt3  = (unsigned*)(ws);
    unsigned* cnt1  = (unsigned*)(ws + 128);
    float* s_raw    = (float*)(ws + 4 * 1024);
    float* yW       = (float*)(ws + 68 * 1024);
    float* score2   = (float*)(ws + 196 * 1024);
    float* xWy      = (float*)(ws + 260 * 1024);

    // Zero counters + atomic accumulation buffers in one memset (196 KiB).
    (void)hipMemsetAsync(d_ws, 0, 196 * 1024, stream);

    k1_proj_sm<<<dim3(Xc / 256, Yc / 32), 256, 0, stream>>>(
        weight, yv, wa_h, s_raw, yW, score2, cnt1);
    k3_dot_lsm<<<dim3(Lc / 16, Bc), 256, 0, stream>>>(
        x, yW, score2, bias, actions, xm, xWy, out, cnt3);
}

// Round 2
// 211.547 us; speedup vs baseline: 2.4929x; 2.4929x over previous
//
#include <hip/hip_runtime.h>
#include <math.h>

// Problem constants (fixed by the reference).
constexpr int Ac = 16;    // actions
constexpr int Bc = 32;    // batch
constexpr int Lc = 1024;  // sequence
constexpr int Xc = 1024;  // x feature
constexpr int Yc = 1024;  // y feature
constexpr int Cc = Ac + Bc;  // 48 combined coefficient rows

// Native clang vector type — __builtin_nontemporal_load requires this.
typedef float vfloat4 __attribute__((ext_vector_type(4)));

// ---------------------------------------------------------------------------
// Wave/block reduction helpers (wave = 64 lanes on CDNA)
// ---------------------------------------------------------------------------
__device__ __forceinline__ float waveReduceSum(float v) {
#pragma unroll
    for (int off = 32; off > 0; off >>= 1) v += __shfl_down(v, off, 64);
    return v;
}

__device__ __forceinline__ float waveReduceMax(float v) {
#pragma unroll
    for (int off = 32; off > 0; off >>= 1) v = fmaxf(v, __shfl_down(v, off, 64));
    return v;
}

// ---------------------------------------------------------------------------
// k1: O[48,X] = C[48,Y] @ W[Y,X]; C rows 0..15 = wa_h, rows 16..47 = y.
// O rows 0..15 -> s_raw (pre-softmax scores), rows 16..47 -> yW.
// grid (X/256=4, Y/32=32) = 128 blocks. Coef chunk [48x32] in LDS,
// 32 weight values prefetched per thread, 1536 FMAs, 48 atomicAdds.
// EXACT round-0 measured-best version. (R5 lesson: NO __threadfence here —
// agent-scope release = buffer_wbl2 per block, catastrophic. Kernel boundary
// is the free coherence point.)
// ---------------------------------------------------------------------------
__global__ __launch_bounds__(256) void k1_proj(
        const float* __restrict__ weight, const float* __restrict__ yv,
        const float* __restrict__ wa_h, float* __restrict__ s_raw,
        float* __restrict__ yW) {
    const int x  = blockIdx.x * 256 + threadIdx.x;
    const int y0 = blockIdx.y * 32;

    __shared__ float cLDS[Cc][32];  // 6 KiB

    // Cooperative coef load: 1536 elements, 6 per thread (coalesced).
#pragma unroll
    for (int k = 0; k < 6; ++k) {
        const int idx = threadIdx.x + k * 256;
        const int row = idx >> 5;
        const int col = idx & 31;
        cLDS[row][col] = (row < Ac) ? wa_h[row * Yc + y0 + col]
                                    : yv[(row - Ac) * Yc + y0 + col];
    }

    // Prefetch this thread's 32 weight values (independent, coalesced).
    float w[32];
#pragma unroll
    for (int t = 0; t < 32; ++t) w[t] = weight[(size_t)(y0 + t) * Xc + x];

    __syncthreads();

    float acc[Cc];
#pragma unroll
    for (int j = 0; j < Cc; ++j) acc[j] = 0.0f;

    const float4* cvec = (const float4*)cLDS;
#pragma unroll
    for (int j = 0; j < Cc; ++j) {
#pragma unroll
        for (int q = 0; q < 8; ++q) {
            const float4 c = cvec[j * 8 + q];  // LDS b128 broadcast (free)
            acc[j] = fmaf(w[q * 4 + 0], c.x, acc[j]);
            acc[j] = fmaf(w[q * 4 + 1], c.y, acc[j]);
            acc[j] = fmaf(w[q * 4 + 2], c.z, acc[j]);
            acc[j] = fmaf(w[q * 4 + 3], c.w, acc[j]);
        }
    }

#pragma unroll
    for (int j = 0; j < Ac; ++j) atomicAdd(&s_raw[j * Xc + x], acc[j]);
#pragma unroll
    for (int j = Ac; j < Cc; ++j) atomicAdd(&yW[(j - Ac) * Xc + x], acc[j]);
}

// ---------------------------------------------------------------------------
// k3: xWy[b,l] = sum_x x[b,l,x] * Wy[b,x].
// R6 fusion (fence-free): the k2 softmax is recomputed in each block's
// prologue from s_raw (previous-kernel output -> coherent by stream order;
// 4 KB row is L2-resident after first touch). Deletes the k2 dispatch and
// the score2 round-trip. Then Wy = yW*p*inv + bias built in LDS.
// Dot: 4 rows per wave INTERLEAVED (4 accs, loads batched ahead of the
// shuffle reduces) -> 4x outstanding nontemporal loads, 4x fewer LDS reads.
// grid: (L/16, B) = 2048 blocks, 4 waves.
// ---------------------------------------------------------------------------
__global__ __launch_bounds__(256) void k3_dot(
        const float* __restrict__ x, const float* __restrict__ yW,
        const float* __restrict__ s_raw, const float* __restrict__ bias,
        const int* __restrict__ actions, float* __restrict__ xWy) {
    const int b   = blockIdx.y;
    const int l0  = blockIdx.x * 16;
    const int tid  = threadIdx.x;
    const int wave = tid >> 6;
    const int lane = tid & 63;
    __shared__ float Wy[Xc];
    __shared__ float smax[4];
    __shared__ float ssum[4];

    const int act = actions[b];

    // ---- fused k2: softmax of s_raw[act,:] (block-local recompute) ----
    float sv[4];
    float mx = -INFINITY;
#pragma unroll
    for (int k = 0; k < 4; ++k) {
        sv[k] = s_raw[act * Xc + tid + k * 256];
        mx = fmaxf(mx, sv[k]);
    }
    mx = waveReduceMax(mx);
    if (lane == 0) smax[wave] = mx;
    __syncthreads();
    mx = fmaxf(fmaxf(smax[0], smax[1]), fmaxf(smax[2], smax[3]));

    float sum = 0.0f;
#pragma unroll
    for (int k = 0; k < 4; ++k) {
        sv[k] = __expf(sv[k] - mx);
        sum += sv[k];
    }
    sum = waveReduceSum(sum);
    if (lane == 0) ssum[wave] = sum;
    __syncthreads();
    sum = ssum[0] + ssum[1] + ssum[2] + ssum[3];
    const float inv = 1.0f / sum;

    // ---- build Wy in LDS ----
#pragma unroll
    for (int k = 0; k < 4; ++k) {
        const int xi = tid + k * 256;
        Wy[xi] = fmaf(yW[b * Xc + xi], sv[k] * inv, bias[xi]);
    }
    __syncthreads();

    // ---- dot: rows {wave, wave+4, wave+8, wave+12}, interleaved ----
    const float4* WyV = (const float4*)Wy;
    const float* xb = x + ((size_t)b * Lc + l0) * Xc;

    float acc[4] = {0.0f, 0.0f, 0.0f, 0.0f};
#pragma unroll
    for (int k = 0; k < 4; ++k) {
        const int idx = lane + k * 64;
        const float4 wv = WyV[idx];
        vfloat4 xv[4];
#pragma unroll
        for (int rr = 0; rr < 4; ++rr) {
            const int l = wave + rr * 4;
            xv[rr] = __builtin_nontemporal_load(
                (const vfloat4*)(xb + (size_t)l * Xc) + idx);
        }
#pragma unroll
        for (int rr = 0; rr < 4; ++rr) {
            acc[rr] = fmaf(xv[rr].x, wv.x, acc[rr]);
            acc[rr] = fmaf(xv[rr].y, wv.y, acc[rr]);
            acc[rr] = fmaf(xv[rr].z, wv.z, acc[rr]);
            acc[rr] = fmaf(xv[rr].w, wv.w, acc[rr]);
        }
    }
#pragma unroll
    for (int rr = 0; rr < 4; ++rr) {
        const float a = waveReduceSum(acc[rr]);
        if (lane == 0) xWy[b * Lc + l0 + wave + rr * 4] = a;
    }
}

// ---------------------------------------------------------------------------
// k4: out[b,:] = log_softmax_L(where(mask, -inf, xWy[b,:])). grid: B blocks.
// (Exact round-0 version.)
// ---------------------------------------------------------------------------
__global__ __launch_bounds__(256) void k4_logsoftmax(
        const float* __restrict__ xWy, const unsigned char* __restrict__ mask,
        float* __restrict__ out) {
    const int b    = blockIdx.x;
    const int tid  = threadIdx.x;
    const int wave = tid >> 6;
    const int lane = tid & 63;
    __shared__ float smax[4];
    __shared__ float ssum[4];

    float v[4];
    float mx = -INFINITY;
#pragma unroll
    for (int k = 0; k < 4; ++k) {
        const int l = tid + k * 256;
        float t = xWy[b * Lc + l];
        if (mask[b * Lc + l]) t = -INFINITY;
        v[k] = t;
        mx = fmaxf(mx, t);
    }
    mx = waveReduceMax(mx);
    if (lane == 0) smax[wave] = mx;
    __syncthreads();
    mx = fmaxf(fmaxf(smax[0], smax[1]), fmaxf(smax[2], smax[3]));

    float sum = 0.0f;
#pragma unroll
    for (int k = 0; k < 4; ++k) sum += __expf(v[k] - mx);
    sum = waveReduceSum(sum);
    if (lane == 0) ssum[wave] = sum;
    __syncthreads();
    sum = ssum[0] + ssum[1] + ssum[2] + ssum[3];

    const float lse = mx + __logf(sum);
#pragma unroll
    for (int k = 0; k < 4; ++k) out[b * Lc + tid + k * 256] = v[k] - lse;
}

// ---------------------------------------------------------------------------
// Launch. Inputs (setup_inputs order):
//   0 x      [B,L,X] f32      1 y      [B,Y] f32     2 x_mask [B,L] bool
//   3 actions[B] int32        4 weight [Y,X] f32     5 bias   [X] f32
//   6 wa_h   [A,Y,1] f32
// Output: [B,L] f32 log-softmax.
// Workspace layout:
//   [0,64K)     s_raw   A*X f32   (atomic-accumulated, zeroed below)
//   [64K,192K)  yW      B*X f32   (atomic-accumulated, zeroed below)
//   [192K,320K) xWy     B*L f32
// ---------------------------------------------------------------------------
extern "C" void kernel_launch(void* const* d_in, const int* in_sizes, int n_in,
                              void* d_out, int out_size, void* d_ws, size_t ws_size,
                              hipStream_t stream) {
    const float* x          = (const float*)d_in[0];
    const float* yv         = (const float*)d_in[1];
    const unsigned char* xm = (const unsigned char*)d_in[2];
    const int* actions      = (const int*)d_in[3];
    const float* weight     = (const float*)d_in[4];
    const float* bias       = (const float*)d_in[5];
    const float* wa_h       = (const float*)d_in[6];
    float* out              = (float*)d_out;

    char* ws      = (char*)d_ws;
    float* s_raw  = (float*)(ws);
    float* yW     = (float*)(ws + 64 * 1024);
    float* xWy    = (float*)(ws + 192 * 1024);

    // Zero only the atomic accumulation buffers (192 KiB).
    (void)hipMemsetAsync(d_ws, 0, 192 * 1024, stream);

    k1_proj<<<dim3(Xc / 256, Yc / 32), 256, 0, stream>>>(weight, yv, wa_h, s_raw, yW);
    k3_dot<<<dim3(Lc / 16, Bc), 256, 0, stream>>>(x, yW, s_raw, bias, actions, xWy);
    k4_logsoftmax<<<Bc, 256, 0, stream>>>(xWy, xm, out);
}